// Round 8
// baseline (466.339 us; speedup 1.0000x reference)
//
#include <hip/hip_runtime.h>
#include <hip/hip_bf16.h>
#include <math.h>

// MLA forward: B=2, S=2048, D=2048, H=16, KV_RANK=512, NOPE=128, ROPE=64
#define B_ 2
#define S_ 2048
#define H_ 16
#define SCALE_ 0.07216878364870323f   // 192^-0.5
#define SL2_ (0.07216878364870323f * 1.4426950408889634f)  // scale * log2(e)
#define EPS_ 1.1920929e-07f
#define M0_ 8.0f                      // constant exp2 shift (cancels in o/l)

typedef __attribute__((ext_vector_type(8))) short bf16x8;
typedef __attribute__((ext_vector_type(4))) float f32x4;
union U4 { uint4 u; bf16x8 v; f32x4 f; };

__device__ __forceinline__ uint bfbits(float x) {   // f32 -> bf16 bits, RNE
    uint u = __float_as_uint(x);
    return (u + 0x7fffu + ((u >> 16) & 1u)) >> 16;
}
__device__ __forceinline__ uint pack2bf(float a, float b) {
    return bfbits(a) | (bfbits(b) << 16);
}
__device__ __forceinline__ uint cvtpk(float a, float b) {  // 1 VALU op, RNE
    uint r;
    asm("v_cvt_pk_bf16_f32 %0, %1, %2" : "=v"(r) : "v"(a), "v"(b));
    return r;
}
__device__ __forceinline__ void gld_lds16(const ushort* g, ushort* l) {
    // async global->LDS DMA, 16B/lane; LDS dest = wave-uniform base + lane*16
    __builtin_amdgcn_global_load_lds(
        (const __attribute__((address_space(1))) uint*)g,
        (__attribute__((address_space(3))) uint*)l, 16, 0, 0);
}

// ---------------------------------------------------------------------------
// MFMA bf16 GEMM (NT): C[m,n] = scale * sum_k A[m,k]*B[n,k] + bias[n]
// 128x128 tile, BK=32, 256 thr (4 waves 2x2 of 64x64), 16x16x32 MFMA.
// SINGLE-buffered K-loop (2 barriers/step): measured faster than explicit
// dbuf on this structure (r7: 87 vs 80.7 us — compiler + 3 blk/CU wave-level
// overlap already hide staging; guide m99/m100/m141).
// z decomposed as z1 = z % zDiv (stride *Off1), z2 = z / zDiv (stride *Off2).
// XCD-bijective tile swizzle when (gx*gy)%8==0 (L2 panel locality).
// OM: 0 = f32 linear (+bias,scale)
//     2 = khimg fragment layout (z1=h, z2=b)
//     3 = vhimg fragment layout (z1=h, z2=b)
//     4 = merged q+kv: cn<3072 -> q192 bf16 (bias+RoPE+SL2, freqs);
//         cn>=3072 -> raw f32 to Cv2 (kv_raw, stride 640)
// ---------------------------------------------------------------------------
template<int OM>
__global__ __launch_bounds__(256) void mgemm(
    const ushort* __restrict__ A, int lda, long long aOff1, long long aOff2,
    const ushort* __restrict__ Bm, int ldb, long long bOff1, long long bOff2,
    const float* __restrict__ bias, float scale,
    void* __restrict__ Cv, int ldc, long long cOff1, long long cOff2,
    int K, int zDiv, const float* __restrict__ freqs, float* __restrict__ Cv2)
{
    __shared__ ushort As[128 * 32];
    __shared__ ushort Bs[128 * 32];

    const int z = blockIdx.z;
    const int z1 = z % zDiv, z2 = z / zDiv;
    A  += z1 * aOff1 + z2 * aOff2;
    Bm += z1 * bOff1 + z2 * bOff2;
    const long long cBase = z1 * cOff1 + z2 * cOff2;

    // XCD-bijective swizzle over the (x,y) tile space
    int bx = blockIdx.x, by = blockIdx.y;
    {
        const int gx = gridDim.x, total = gx * gridDim.y;
        if ((total & 7) == 0) {
            const int flat = bx + gx * by;
            const int nx = total >> 3;
            const int flat2 = (flat & 7) * nx + (flat >> 3);
            bx = flat2 % gx;
            by = flat2 / gx;
        }
    }
    const int n0 = bx * 128;
    const int m0 = by * 128;
    const int tid = threadIdx.x;
    const int w   = tid >> 6;
    const int l   = tid & 63;
    const int m   = l & 15;
    const int q4  = l >> 4;
    const int mw  = (w & 1) * 64;
    const int nw  = (w >> 1) * 64;
    const int sr  = l >> 2;
    const int sc  = l & 3;

    f32x4 acc[4][4];
#pragma unroll
    for (int i = 0; i < 4; ++i)
#pragma unroll
        for (int j = 0; j < 4; ++j) acc[i][j] = (f32x4){0.f, 0.f, 0.f, 0.f};

    for (int k0 = 0; k0 < K; k0 += 32) {
#pragma unroll
        for (int jj = 0; jj < 2; ++jj) {
            const int slot = w * 2 + jj;
            const int row  = slot * 16 + sr;
            const int g    = sc ^ ((row >> 1) & 3);
            gld_lds16(&A[(long long)(m0 + row) * lda + k0 + g * 8], &As[slot * 512]);
            gld_lds16(&Bm[(long long)(n0 + row) * ldb + k0 + g * 8], &Bs[slot * 512]);
        }
        __syncthreads();

        U4 af[4], bf[4];
#pragma unroll
        for (int i = 0; i < 4; ++i) {
            const int ra = mw + i * 16 + m;
            af[i].u = *(const uint4*)&As[ra * 32 + (q4 ^ ((ra >> 1) & 3)) * 8];
            const int rb = nw + i * 16 + m;
            bf[i].u = *(const uint4*)&Bs[rb * 32 + (q4 ^ ((rb >> 1) & 3)) * 8];
        }
#pragma unroll
        for (int i = 0; i < 4; ++i)
#pragma unroll
            for (int j = 0; j < 4; ++j)
                acc[i][j] = __builtin_amdgcn_mfma_f32_16x16x32_bf16(
                    af[i].v, bf[j].v, acc[i][j], 0, 0, 0);
        __syncthreads();
    }

#pragma unroll
    for (int j = 0; j < 4; ++j) {
        const int cn = n0 + nw + j * 16 + m;
        const bool kvReg = (OM == 4) && (cn >= 3072);   // block-uniform (3072=24*128)
        const float bv = (bias && !kvReg) ? bias[cn] : 0.0f;
        const int d192 = cn % 192;             // 16-aligned windows: wave-uniform region
        const bool ropeW = (OM == 4) && !kvReg && (d192 >= 128);
        const int ri = (d192 - 128) >> 1;      // rope pair index (lane-varying)
        const bool evn = !(cn & 1);
#pragma unroll
        for (int i2 = 0; i2 < 4; ++i2) {
            const int rw = m0 + mw + i2 * 16 + q4 * 4;
#pragma unroll
            for (int r = 0; r < 4; ++r) {
                if (OM == 0) {
                    const float val = acc[i2][j][r] * scale + bv;
                    ((float*)Cv)[cBase + (long long)(rw + r) * ldc + cn] = val;
                } else if (OM == 4) {
                    if (kvReg) {
                        ((float*)Cv2)[(long long)(rw + r) * 640 + (cn - 3072)] =
                            acc[i2][j][r];
                    } else {
                        float val = acc[i2][j][r] + bv;      // bias before rope
                        if (ropeW) {
                            const float pv = __shfl_xor(val, 1, 64);
                            const float a  = evn ? val : pv;
                            const float b  = evn ? pv : val;
                            const int s = (rw + r) & 2047;
                            float cs, sn;
                            __sincosf(freqs[s * 32 + ri], &sn, &cs);
                            val = evn ? (a * cs - b * sn) : (a * sn + b * cs);
                        }
                        ((ushort*)Cv)[(long long)(rw + r) * 3072 + cn] =
                            (ushort)bfbits(val * SL2_);
                    }
                } else if (OM == 2) {
                    const float val = acc[i2][j][r] * scale + bv;
                    // khimg[b][t>>5][h][(d>>5)*2 + ((t>>4)&1)][(d>>3)&3][t&15][d&7]
                    const int t = rw + r, d = cn;
                    const long long idx =
                        ((((long long)(z2 * 64 + (t >> 5)) * 16 + z1) * 8
                          + (d >> 5) * 2 + ((t >> 4) & 1)) * 64
                         + ((d >> 3) & 3) * 16 + (t & 15)) * 8 + (d & 7);
                    ((ushort*)Cv)[idx] = (ushort)bfbits(val);
                } else {
                    const float val = acc[i2][j][r] * scale + bv;
                    // vhimg[b][t>>5][h][d>>4][(t>>3)&3][d&15][t&7]
                    const int d = rw + r, t = cn;
                    const long long idx =
                        ((((long long)(z2 * 64 + (t >> 5)) * 16 + z1) * 8
                          + (d >> 4)) * 64
                         + ((t >> 3) & 3) * 16 + (d & 15)) * 8 + (t & 7);
                    ((ushort*)Cv)[idx] = (ushort)bfbits(val);
                }
            }
        }
    }
}

// ---------------------------------------------------------------------------
// Fused f32 -> bf16 conversions (one launch). wq_bf and wkva_bf are written
// CONTIGUOUSLY so the merged q+kv GEMM sees one (3712,2048) B matrix.
// ---------------------------------------------------------------------------
__global__ __launch_bounds__(256) void conv_all(
    const float* __restrict__ x, const float* __restrict__ wq,
    const float* __restrict__ wkva, const float* __restrict__ wo,
    const float* __restrict__ wkvb,
    ushort* __restrict__ x_bf, ushort* __restrict__ wq_bf,
    ushort* __restrict__ wkva_bf, ushort* __restrict__ wo_bf,
    ushort* __restrict__ wkvbK, ushort* __restrict__ wkvbV)
{
    const int bid = blockIdx.x;
    const int tid = threadIdx.x;
    if (bid < 8192) {                       // x: (4096,2048)
        const long long i = ((long long)bid * 256 + tid) * 4;
        float4 v = *(const float4*)&x[i];
        uint2 p; p.x = pack2bf(v.x, v.y); p.y = pack2bf(v.z, v.w);
        *(uint2*)&x_bf[i] = p;
    } else if (bid < 14336) {               // wq: (3072,2048)
        const long long i = ((long long)(bid - 8192) * 256 + tid) * 4;
        float4 v = *(const float4*)&wq[i];
        uint2 p; p.x = pack2bf(v.x, v.y); p.y = pack2bf(v.z, v.w);
        *(uint2*)&wq_bf[i] = p;
    } else if (bid < 15616) {               // wkva: (576,2048) pad to 640
        const int i = ((bid - 14336) * 256 + tid) * 4;
        const int r = i >> 11;
        uint2 p = make_uint2(0u, 0u);
        if (r < 576) {
            float4 v = *(const float4*)&wkva[i];
            p.x = pack2bf(v.x, v.y); p.y = pack2bf(v.z, v.w);
        }
        *(uint2*)&wkva_bf[i] = p;
    } else if (bid < 19712) {               // wo: (2048,2048)
        const long long i = ((long long)(bid - 15616) * 256 + tid) * 4;
        float4 v = *(const float4*)&wo[i];
        uint2 p; p.x = pack2bf(v.x, v.y); p.y = pack2bf(v.z, v.w);
        *(uint2*)&wo_bf[i] = p;
    } else if (bid < 20736) {               // wkv_b rows [0:128) per head -> K
        const int i = ((bid - 19712) * 256 + tid) * 4;
        const int h = i >> 16, rem = i & 65535;
        float4 v = *(const float4*)&wkvb[((long long)(h * 256)) * 512 + rem];
        uint2 p; p.x = pack2bf(v.x, v.y); p.y = pack2bf(v.z, v.w);
        *(uint2*)&wkvbK[i] = p;
    } else {                                // wkv_b rows [128:256) per head -> V
        const int i = ((bid - 20736) * 256 + tid) * 4;
        const int h = i >> 16, rem = i & 65535;
        float4 v = *(const float4*)&wkvb[((long long)(h * 256 + 128)) * 512 + rem];
        uint2 p; p.x = pack2bf(v.x, v.y); p.y = pack2bf(v.z, v.w);
        *(uint2*)&wkvbV[i] = p;
    }
}

// ---------------------------------------------------------------------------
// kv post: bias add + rmsnorm(kv[:512]) -> kv_h bf16; rope(kv[512:576])
// written DIRECTLY in rimg fragment layout.
// ---------------------------------------------------------------------------
__global__ __launch_bounds__(64) void kv_post_kernel(
    const float* __restrict__ kv_raw, const float* __restrict__ bias,
    const float* __restrict__ w, const float* __restrict__ freqs,
    ushort* __restrict__ kv_h, uint* __restrict__ rimg)
{
    const int bs = blockIdx.x;
    const int lane = threadIdx.x;
    const float* src = kv_raw + (long long)bs * 640;
    ushort* dst = kv_h + (long long)bs * 576;

    const int c = 4 * lane;
    float4 v0 = *(const float4*)&src[c];
    float4 v1 = *(const float4*)&src[256 + c];
    float4 b0 = *(const float4*)&bias[c];
    float4 b1 = *(const float4*)&bias[256 + c];
    v0.x += b0.x; v0.y += b0.y; v0.z += b0.z; v0.w += b0.w;
    v1.x += b1.x; v1.y += b1.y; v1.z += b1.z; v1.w += b1.w;
    float ss = v0.x * v0.x + v0.y * v0.y + v0.z * v0.z + v0.w * v0.w +
               v1.x * v1.x + v1.y * v1.y + v1.z * v1.z + v1.w * v1.w;
#pragma unroll
    for (int o = 32; o; o >>= 1) ss += __shfl_xor(ss, o, 64);
    const float rs = rsqrtf(ss * (1.0f / 512.0f) + EPS_);

    float4 w0 = *(const float4*)&w[c];
    float4 w1 = *(const float4*)&w[256 + c];
    uint2 p0, p1;
    p0.x = pack2bf(v0.x * rs * w0.x, v0.y * rs * w0.y);
    p0.y = pack2bf(v0.z * rs * w0.z, v0.w * rs * w0.w);
    p1.x = pack2bf(v1.x * rs * w1.x, v1.y * rs * w1.y);
    p1.y = pack2bf(v1.z * rs * w1.z, v1.w * rs * w1.w);
    *(uint2*)&dst[c] = p0;
    *(uint2*)&dst[256 + c] = p1;

    if (lane < 32) {
        const int b = bs >> 11, s = bs & 2047;
        const int j = lane;
        const float f = freqs[s * 32 + j];
        float cs, sn;
        __sincosf(f, &sn, &cs);
        const float a  = src[512 + 2 * j]     + bias[512 + 2 * j];
        const float b2 = src[512 + 2 * j + 1] + bias[512 + 2 * j + 1];
        const uint p = pack2bf(a * cs - b2 * sn, a * sn + b2 * cs);
        const long long idx =
            (((long long)(b * 64 + (s >> 5)) * 4 + (j >> 4) * 2 + ((s >> 4) & 1)) * 64
             + ((j >> 2) & 3) * 16 + (s & 15)) * 4 + (j & 3);
        rimg[idx] = p;
    }
}

// ---------------------------------------------------------------------------
// MFMA flash attention v13 (unchanged): split-T + XCD-grouped.
// Grid (32 = h + 16b, 8 = pair, 2 = parity) = 512 blocks = 2/CU, uniform
// 34 tiles each; f32 partials + combine (constant-shift softmax).
// ---------------------------------------------------------------------------
__global__ __launch_bounds__(256, 2) void attn_kernel(
    const ushort* __restrict__ q192,  // (B,S,H,192), q*scale*log2e
    const uint4*  __restrict__ khimg, // (B,64,16,8,64) K_h frag chunks
    const uint4*  __restrict__ rimg,  // (B,64,4,64)   k_pe frag chunks
    const uint4*  __restrict__ vhimg, // (B,64,16,8,64) V_h^T frag chunks
    float* __restrict__ part_o,       // (512*2,128,128) f32 partial O
    float* __restrict__ part_l)       // (512*2,128)     f32 partial l
{
    __shared__ uint buf[2][20 * 256];   // 2 x 20 KB

    const int hb   = blockIdx.x;          // 0..31: h + 16*b (XCD = hb & 7)
    const int h    = hb & 15;
    const int b    = hb >> 4;
    const int p    = blockIdx.y;          // 0..7 (chunk pair)
    const int par  = blockIdx.z;          // tile parity
    const int tid  = threadIdx.x;
    const int wid  = tid >> 6;            // 0..3
    const int lane = tid & 63;
    const int m    = lane & 15;
    const int q4   = lane >> 4;
    const bool odd = q4 & 1;

    auto stage = [&](int bs, int it) {
        const long long tb = (long long)(b * 64 + it);
        const uint4* kb = khimg + ((tb * 16 + h) * 8) * 64;
        const uint4* rb = rimg  + (tb * 4) * 64;
        const uint4* vb = vhimg + ((tb * 16 + h) * 8) * 64;
        ushort* l = (ushort*)&buf[bs][0];
        gld_lds16((const ushort*)(kb + (wid    ) * 64 + lane), l + (wid     ) * 512);
        gld_lds16((const ushort*)(kb + (wid + 4) * 64 + lane), l + (wid +  4) * 512);
        gld_lds16((const ushort*)(rb + (wid    ) * 64 + lane), l + (wid +  8) * 512);
        gld_lds16((const ushort*)(vb + (wid    ) * 64 + lane), l + (wid + 12) * 512);
        gld_lds16((const ushort*)(vb + (wid + 4) * 64 + lane), l + (wid + 16) * 512);
    };

    int cur = 0;
    for (int pass = 0; pass < 2; ++pass) {
        const int chunk = pass ? p : (15 - p);
        const int row0a = chunk * 128 + wid * 16;
        const int row0b = row0a + 64;
        const int sRa   = row0a + m;
        const int sRb   = row0b + m;

        U4 qfa[6], qfb[6];
        {
            const uint4* qpa = (const uint4*)(q192 + ((long long)(b * S_ + sRa) * H_ + h) * 192);
            const uint4* qpb = (const uint4*)(q192 + ((long long)(b * S_ + sRb) * H_ + h) * 192);
#pragma unroll
            for (int f = 0; f < 6; ++f) { qfa[f].u = qpa[f * 4 + q4]; qfb[f].u = qpb[f * 4 + q4]; }
        }

        f32x4 oA[8], oB[8];
#pragma unroll
        for (int c = 0; c < 8; ++c) {
            oA[c] = (f32x4){0.f, 0.f, 0.f, 0.f};
            oB[c] = (f32x4){0.f, 0.f, 0.f, 0.f};
        }
        float lA = 0.0f, lB = 0.0f;

        auto softpack = [&](const f32x4 s0, const f32x4 s1, int t0v, int rw0,
                            float& lac) -> U4 {
            float p00, p01, p02, p03, p10, p11, p12, p13;
            if (t0v + 31 <= rw0) {            // fully unmasked tile
                p00 = exp2f(s0[0] - M0_); p01 = exp2f(s0[1] - M0_);
                p02 = exp2f(s0[2] - M0_); p03 = exp2f(s0[3] - M0_);
                p10 = exp2f(s1[0] - M0_); p11 = exp2f(s1[1] - M0_);
                p12 = exp2f(s1[2] - M0_); p13 = exp2f(s1[3] - M0_);
            } else {                          // diagonal tile
                const int sR = rw0 + m;
                const int tb0 = t0v + q4 * 4;
                const int tb1 = tb0 + 16;
                p00 = (tb0 + 0 <= sR) ? exp2f(s0[0] - M0_) : 0.0f;
                p01 = (tb0 + 1 <= sR) ? exp2f(s0[1] - M0_) : 0.0f;
                p02 = (tb0 + 2 <= sR) ? exp2f(s0[2] - M0_) : 0.0f;
                p03 = (tb0 + 3 <= sR) ? exp2f(s0[3] - M0_) : 0.0f;
                p10 = (tb1 + 0 <= sR) ? exp2f(s1[0] - M0_) : 0.0f;
                p11 = (tb1 + 1 <= sR) ? exp2f(s1[1] - M0_) : 0.0f;
                p12 = (tb1 + 2 <= sR) ? exp2f(s1[2] - M0_) : 0.0f;
                p13 = (tb1 + 3 <= sR) ? exp2f(s1[3] - M0_) : 0.0f;
            }
            lac += (p00 + p01) + (p02 + p03) + (p10 + p11) + (p12 + p13);
            uint X0 = cvtpk(p00, p01), X1 = cvtpk(p02, p03);
            uint Y0 = cvtpk(p10, p11), Y1 = cvtpk(p12, p13);
            asm("v_permlane32_swap_b32 %0, %1" : "+v"(X0), "+v"(Y0));
            asm("v_permlane32_swap_b32 %0, %1" : "+v"(X1), "+v"(Y1));
            uint u0 = odd ? X0 : Y0;
            uint u1 = odd ? X1 : Y1;
            uint w0 = (uint)__builtin_amdgcn_ds_swizzle((int)u0, 0x401F); // xor 16
            uint w1 = (uint)__builtin_amdgcn_ds_swizzle((int)u1, 0x401F);
            U4 bb;
            bb.u.x = odd ? w0 : X0;
            bb.u.y = odd ? w1 : X1;
            bb.u.z = odd ? Y0 : w0;
            bb.u.w = odd ? Y1 : w1;
            return bb;
        };

        const int nT2 = 2 * chunk + 2;        // parity-tiles in this pass
        __syncthreads();                 // all reads of prev pass's LDS done
        stage(cur, par);

        for (int v = 0; v < nT2; ++v) {
            const int it = 2 * v + par;
            const int t0 = it * 32;
            __syncthreads();             // drains vmcnt(0): buf[cur] staged
            if (v + 1 < nT2) stage(cur ^ 1, it + 2);   // overlap under compute
            __builtin_amdgcn_sched_barrier(0);

            const uint* bb0 = &buf[cur][0];
            const int abase = lane * 4;
            const bool liveB = (t0 <= row0b + 15);
            const bool liveA = (t0 <= row0a + 15);
            const bool twoA  = (t0 < row0a);
            const bool twoB  = (t0 < row0b);

            if (liveB) {
                f32x4 sA0 = (f32x4){0.f,0.f,0.f,0.f}, sA1 = (f32x4){0.f,0.f,0.f,0.f};
                f32x4 sB0 = (f32x4){0.f,0.f,0.f,0.f}, sB1 = (f32x4){0.f,0.f,0.f,0.f};

                if (twoA) {     // both substrips full: 4 MFMAs per read-pair
#pragma unroll
                    for (int f = 0; f < 6; ++f) {
                        const int ck = (f < 4) ? f * 2 : (f - 4) * 2 + 8;
                        U4 a0, a1;
                        a0.u = *(const uint4*)&bb0[ck * 256 + abase];
                        a1.u = *(const uint4*)&bb0[(ck + 1) * 256 + abase];
                        sA0 = __builtin_amdgcn_mfma_f32_16x16x32_bf16(a0.v, qfa[f].v, sA0, 0, 0, 0);
                        sB0 = __builtin_amdgcn_mfma_f32_16x16x32_bf16(a0.v, qfb[f].v, sB0, 0, 0, 0);
                        sA1 = __builtin_amdgcn_mfma_f32_16x16x32_bf16(a1.v, qfa[f].v, sA1, 0, 0, 0);
                        sB1 = __builtin_amdgcn_mfma_f32_16x16x32_bf16(a1.v, qfb[f].v, sB1, 0, 0, 0);
                    }
                } else {        // A diagonal/dead; B full or diagonal
#pragma unroll
                    for (int f = 0; f < 6; ++f) {
                        const int ck = (f < 4) ? f * 2 : (f - 4) * 2 + 8;
                        U4 a0;
                        a0.u = *(const uint4*)&bb0[ck * 256 + abase];
                        if (liveA)
                            sA0 = __builtin_amdgcn_mfma_f32_16x16x32_bf16(a0.v, qfa[f].v, sA0, 0, 0, 0);
                        sB0 = __builtin_amdgcn_mfma_f32_16x16x32_bf16(a0.v, qfb[f].v, sB0, 0, 0, 0);
                        if (twoB) {
                            U4 a1;
                            a1.u = *(const uint4*)&bb0[(ck + 1) * 256 + abase];
                            sB1 = __builtin_amdgcn_mfma_f32_16x16x32_bf16(a1.v, qfb[f].v, sB1, 0, 0, 0);
                        }
                    }
                }

                U4 bbB = softpack(sB0, sB1, t0, row0b, lB);
                if (liveA) {
                    U4 bbA = softpack(sA0, sA1, t0, row0a, lA);
#pragma unroll
                    for (int c = 0; c < 8; ++c) {
                        U4 av; av.u = *(const uint4*)&bb0[(12 + c) * 256 + abase];
                        oB[c] = __builtin_amdgcn_mfma_f32_16x16x32_bf16(av.v, bbB.v, oB[c], 0, 0, 0);
                        oA[c] = __builtin_amdgcn_mfma_f32_16x16x32_bf16(av.v, bbA.v, oA[c], 0, 0, 0);
                    }
                } else {
#pragma unroll
                    for (int c = 0; c < 8; ++c) {
                        U4 av; av.u = *(const uint4*)&bb0[(12 + c) * 256 + abase];
                        oB[c] = __builtin_amdgcn_mfma_f32_16x16x32_bf16(av.v, bbB.v, oB[c], 0, 0, 0);
                    }
                }
            }
            cur ^= 1;
        }

        // ---- epilogue: reduce l across q4 groups; store f32 partials
        lA += __shfl_xor(lA, 16, 64);
        lA += __shfl_xor(lA, 32, 64);
        lB += __shfl_xor(lB, 16, 64);
        lB += __shfl_xor(lB, 32, 64);

        const int cid  = (b * 16 + h) * 16 + chunk;
        const int slot = cid * 2 + par;
        float* po = part_o + (long long)slot * 16384;
        const int rA = wid * 16 + m;
        const int rB = rA + 64;
#pragma unroll
        for (int c = 0; c < 8; ++c) {
            *(f32x4*)&po[rA * 128 + c * 16 + q4 * 4] = oA[c];
            *(f32x4*)&po[rB * 128 + c * 16 + q4 * 4] = oB[c];
        }
        if (q4 == 0) {
            part_l[slot * 128 + rA] = lA;
            part_l[slot * 128 + rB] = lB;
        }
    }
}

// ---------------------------------------------------------------------------
// Combine the two parity partials: o = (o0+o1)/(l0+l1) -> o_h bf16.
// ---------------------------------------------------------------------------
__global__ __launch_bounds__(256) void combine_kernel(
    const float* __restrict__ part_o, const float* __restrict__ part_l,
    ushort* __restrict__ o_h)
{
    const int idx = blockIdx.x * 256 + threadIdx.x;    // 0..2,097,151
    const int d4  = (idx & 31) * 4;                    // 0..124
    const int r   = (idx >> 5) & 127;
    const int cid = idx >> 12;                         // 0..511
    const int chunk = cid & 15, h = (cid >> 4) & 15, b = cid >> 8;
    const long long s0 = (long long)(cid * 2) * 16384 + r * 128 + d4;
    float4 a = *(const float4*)&part_o[s0];
    float4 c = *(const float4*)&part_o[s0 + 16384];
    const float l = part_l[cid * 256 + r] + part_l[cid * 256 + 128 + r];
    const float inv = 1.0f / l;
    uint2 pk;
    pk.x = cvtpk((a.x + c.x) * inv, (a.y + c.y) * inv);
    pk.y = cvtpk((a.z + c.z) * inv, (a.w + c.w) * inv);
    const int s = chunk * 128 + r;
    *(uint2*)&o_h[(((long long)(b * S_ + s)) * H_ + h) * 128 + d4] = pk;
}

// ---------------------------------------------------------------------------
extern "C" void kernel_launch(void* const* d_in, const int* in_sizes, int n_in,
                              void* d_out, int out_size, void* d_ws, size_t ws_size,
                              hipStream_t stream)
{
    const float* x         = (const float*)d_in[0];
    const float* freqs     = (const float*)d_in[1];
    // d_in[2] = mask (unused: causal handled analytically)
    const float* wq_w      = (const float*)d_in[3];
    const float* wq_b      = (const float*)d_in[4];
    const float* wkv_a_w   = (const float*)d_in[5];
    const float* wkv_a_b   = (const float*)d_in[6];
    const float* kv_norm_w = (const float*)d_in[7];
    const float* wkv_b_w   = (const float*)d_in[8];
    const float* wo_w      = (const float*)d_in[9];
    const float* wo_b      = (const float*)d_in[10];
    float* out = (float*)d_out;

    // ---- workspace layout: persistent region + overlaid scratch
    char* w = (char*)d_ws;
    ushort* wo_bf   = (ushort*)w;  w += 8388608;    // (2048,2048) bf16
    uint4*  khimg   = (uint4*)w;   w += 16777216;   // (B,64,16,8,64)
    uint4*  vhimg   = (uint4*)w;   w += 16777216;   // (B,64,16,8,64)
    uint4*  rimg    = (uint4*)w;   w += 524288;     // (B,64,4,64)
    ushort* q192    = (ushort*)w;  w += 25165824;   // (4096,16,192) bf16
    ushort* o_h     = (ushort*)w;  w += 16777216;   // (4096,16,128) bf16
    char* SCR = w;                                  // scratch: ~68 MB
    // phase 1 (conv + merged GEMM):
    ushort* x_bf    = (ushort*)(SCR);               // 16,777,216
    ushort* wq_bf   = (ushort*)(SCR + 16777216);    // 12,582,912  } contiguous:
    ushort* wkva_bf = (ushort*)(SCR + 29360128);    //  2,621,440  } (3712,2048) B
    ushort* wkvbK   = (ushort*)(SCR + 31981568);    //  2,097,152 (live thru step4)
    ushort* wkvbV   = (ushort*)(SCR + 34078720);    //  2,097,152 (live thru step4)
    float*  kv_raw  = (float*)(SCR + 36175872);     // 10,485,760 (dead after step3)
    // phase 2 overlay (x_bf dead after merged GEMM):
    ushort* kv_h    = (ushort*)(SCR);               //  4,718,592 (over x_bf)
    // phase 3 overlays (attn partials; everything above dead by attn):
    float*  part_o  = (float*)(SCR);                // 67,108,864
    float*  part_l  = (float*)(SCR + 67108864);     //    524,288

    dim3 blk(256);

    // 0) all f32->bf16 conversions, one launch
    conv_all<<<dim3(21760), blk, 0, stream>>>(
        x, wq_w, wkv_a_w, wo_w, wkv_b_w,
        x_bf, wq_bf, wkva_bf, wo_bf, wkvbK, wkvbV);

    // 1) MERGED: [q192 | kv_raw] = x @ [wq; wkv_a]^T  (N = 3712 = 29 tiles)
    //    cn<3072: q192 bf16 (+wq_b, rope, *scale*log2e); cn>=3072: kv_raw f32
    mgemm<4><<<dim3(29, 32, 1), blk, 0, stream>>>(
        x_bf, 2048, 0LL, 0LL, wq_bf, 2048, 0LL, 0LL, wq_b, 1.0f,
        q192, 3072, 0LL, 0LL, 2048, 1, freqs, kv_raw);

    // 2) bias + rmsnorm -> kv_h; rope -> rimg directly
    kv_post_kernel<<<dim3(4096), dim3(64), 0, stream>>>(
        kv_raw, wkv_a_b, kv_norm_w, freqs, kv_h, (uint*)rimg);

    // 3) per-head K/V projections writing DIRECTLY in fragment-image layout:
    mgemm<2><<<dim3(1, 16, 32), blk, 0, stream>>>(
        kv_h, 576, 0LL, (long long)S_ * 576,
        wkvbK, 512, 65536LL, 0LL, nullptr, 1.0f,
        khimg, 0, 0LL, 0LL, 512, 16, nullptr, nullptr);
    mgemm<3><<<dim3(16, 1, 32), blk, 0, stream>>>(
        wkvbV, 512, 65536LL, 0LL,
        kv_h, 576, 0LL, (long long)S_ * 576, nullptr, 1.0f,
        vhimg, 0, 0LL, 0LL, 512, 16, nullptr, nullptr);

    // 4) MFMA flash attention v13 (split-T, XCD-grouped) -> f32 partials
    attn_kernel<<<dim3(32, 8, 2), blk, 0, stream>>>(
        q192, khimg, rimg, vhimg, part_o, part_l);

    // 4b) combine parity partials -> o_h bf16
    combine_kernel<<<dim3(8192), blk, 0, stream>>>(part_o, part_l, o_h);

    // 5) out = o_h @ wo_w^T + wo_b
    mgemm<0><<<dim3(16, 32, 1), blk, 0, stream>>>(
        o_h, 2048, 0LL, 0LL, wo_bf, 2048, 0LL, 0LL, wo_b, 1.0f,
        out, 2048, 0LL, 0LL, 2048, 1, nullptr, nullptr);
}

// Round 9
// 448.460 us; speedup vs baseline: 1.0399x; 1.0399x over previous
//
#include <hip/hip_runtime.h>
#include <hip/hip_bf16.h>
#include <math.h>

// MLA forward: B=2, S=2048, D=2048, H=16, KV_RANK=512, NOPE=128, ROPE=64
#define B_ 2
#define S_ 2048
#define H_ 16
#define SCALE_ 0.07216878364870323f   // 192^-0.5
#define SL2_ (0.07216878364870323f * 1.4426950408889634f)  // scale * log2(e)
#define EPS_ 1.1920929e-07f
#define M0_ 8.0f                      // constant exp2 shift (cancels in o/l)

typedef __attribute__((ext_vector_type(8))) short bf16x8;
typedef __attribute__((ext_vector_type(4))) float f32x4;
union U4 { uint4 u; bf16x8 v; f32x4 f; };

__device__ __forceinline__ uint bfbits(float x) {   // f32 -> bf16 bits, RNE
    uint u = __float_as_uint(x);
    return (u + 0x7fffu + ((u >> 16) & 1u)) >> 16;
}
__device__ __forceinline__ uint pack2bf(float a, float b) {
    return bfbits(a) | (bfbits(b) << 16);
}
__device__ __forceinline__ uint cvtpk(float a, float b) {  // 1 VALU op, RNE
    uint r;
    asm("v_cvt_pk_bf16_f32 %0, %1, %2" : "=v"(r) : "v"(a), "v"(b));
    return r;
}
__device__ __forceinline__ void gld_lds16(const ushort* g, ushort* l) {
    // async global->LDS DMA, 16B/lane; LDS dest = wave-uniform base + lane*16
    __builtin_amdgcn_global_load_lds(
        (const __attribute__((address_space(1))) uint*)g,
        (__attribute__((address_space(3))) uint*)l, 16, 0, 0);
}

// ---------------------------------------------------------------------------
// MFMA bf16 GEMM (NT): C[m,n] = scale * sum_k A[m,k]*B[n,k] + bias[n]
// 128x128 tile, BK=32, 256 thr (4 waves 2x2 of 64x64), 16x16x32 MFMA.
// SINGLE-buffered K-loop: proven fastest config (r6: 638 TF; r7 dbuf −8%;
// r8 N-merge −38% — both reverted).
// z decomposed as z1 = z % zDiv (stride *Off1), z2 = z / zDiv (stride *Off2).
// XCD-bijective tile swizzle when (gx*gy)%8==0 (L2 panel locality).
// OM: 0 = f32 linear (+bias,scale)
//     1 = q192 bf16: bias + RoPE on cols d%192>=128 + SL2 scale (freqs used)
//     5 = merged per-head K/V projection: tile bx==0 -> khimg, bx==1 -> vhimg
//         (Cv=khimg, Cv2=vhimg; z1=h, z2=b; B = wkv_b native (h,256,512))
// ---------------------------------------------------------------------------
template<int OM>
__global__ __launch_bounds__(256) void mgemm(
    const ushort* __restrict__ A, int lda, long long aOff1, long long aOff2,
    const ushort* __restrict__ Bm, int ldb, long long bOff1, long long bOff2,
    const float* __restrict__ bias, float scale,
    void* __restrict__ Cv, int ldc, long long cOff1, long long cOff2,
    int K, int zDiv, const float* __restrict__ freqs, void* __restrict__ Cv2)
{
    __shared__ ushort As[128 * 32];
    __shared__ ushort Bs[128 * 32];

    const int z = blockIdx.z;
    const int z1 = z % zDiv, z2 = z / zDiv;
    A  += z1 * aOff1 + z2 * aOff2;
    Bm += z1 * bOff1 + z2 * bOff2;
    const long long cBase = z1 * cOff1 + z2 * cOff2;

    // XCD-bijective swizzle over the (x,y) tile space
    int bx = blockIdx.x, by = blockIdx.y;
    {
        const int gx = gridDim.x, total = gx * gridDim.y;
        if ((total & 7) == 0) {
            const int flat = bx + gx * by;
            const int nx = total >> 3;
            const int flat2 = (flat & 7) * nx + (flat >> 3);
            bx = flat2 % gx;
            by = flat2 / gx;
        }
    }
    const int n0 = bx * 128;
    const int m0 = by * 128;
    const int tid = threadIdx.x;
    const int w   = tid >> 6;
    const int l   = tid & 63;
    const int m   = l & 15;
    const int q4  = l >> 4;
    const int mw  = (w & 1) * 64;
    const int nw  = (w >> 1) * 64;
    const int sr  = l >> 2;
    const int sc  = l & 3;

    f32x4 acc[4][4];
#pragma unroll
    for (int i = 0; i < 4; ++i)
#pragma unroll
        for (int j = 0; j < 4; ++j) acc[i][j] = (f32x4){0.f, 0.f, 0.f, 0.f};

    for (int k0 = 0; k0 < K; k0 += 32) {
#pragma unroll
        for (int jj = 0; jj < 2; ++jj) {
            const int slot = w * 2 + jj;
            const int row  = slot * 16 + sr;
            const int g    = sc ^ ((row >> 1) & 3);
            gld_lds16(&A[(long long)(m0 + row) * lda + k0 + g * 8], &As[slot * 512]);
            gld_lds16(&Bm[(long long)(n0 + row) * ldb + k0 + g * 8], &Bs[slot * 512]);
        }
        __syncthreads();

        U4 af[4], bf[4];
#pragma unroll
        for (int i = 0; i < 4; ++i) {
            const int ra = mw + i * 16 + m;
            af[i].u = *(const uint4*)&As[ra * 32 + (q4 ^ ((ra >> 1) & 3)) * 8];
            const int rb = nw + i * 16 + m;
            bf[i].u = *(const uint4*)&Bs[rb * 32 + (q4 ^ ((rb >> 1) & 3)) * 8];
        }
#pragma unroll
        for (int i = 0; i < 4; ++i)
#pragma unroll
            for (int j = 0; j < 4; ++j)
                acc[i][j] = __builtin_amdgcn_mfma_f32_16x16x32_bf16(
                    af[i].v, bf[j].v, acc[i][j], 0, 0, 0);
        __syncthreads();
    }

    const bool isK = (n0 == 0);                // OM=5: tile-uniform K/V select
#pragma unroll
    for (int j = 0; j < 4; ++j) {
        const int cn = n0 + nw + j * 16 + m;
        const float bv = bias ? bias[cn] : 0.0f;
        const int d192 = cn % 192;             // 16-aligned windows: wave-uniform region
        const bool ropeW = (OM == 1) && (d192 >= 128);
        const int ri = (d192 - 128) >> 1;      // rope pair index (lane-varying)
        const bool evn = !(cn & 1);
#pragma unroll
        for (int i2 = 0; i2 < 4; ++i2) {
            const int rw = m0 + mw + i2 * 16 + q4 * 4;
#pragma unroll
            for (int r = 0; r < 4; ++r) {
                if (OM == 0) {
                    const float val = acc[i2][j][r] * scale + bv;
                    ((float*)Cv)[cBase + (long long)(rw + r) * ldc + cn] = val;
                } else if (OM == 1) {
                    float val = acc[i2][j][r] + bv;      // bias before rope
                    if (ropeW) {
                        const float pv = __shfl_xor(val, 1, 64);
                        const float a  = evn ? val : pv;
                        const float b  = evn ? pv : val;
                        const int s = (rw + r) & 2047;
                        float cs, sn;
                        __sincosf(freqs[s * 32 + ri], &sn, &cs);
                        val = evn ? (a * cs - b * sn) : (a * sn + b * cs);
                    }
                    ((ushort*)Cv)[cBase + (long long)(rw + r) * ldc + cn] =
                        (ushort)bfbits(val * SL2_);
                } else {                                  // OM == 5
                    const float val = acc[i2][j][r];
                    const int t = rw + r;
                    if (isK) {
                        // khimg[b][t>>5][h][(d>>5)*2+((t>>4)&1)][(d>>3)&3][t&15][d&7]
                        const int d = cn;
                        const long long idx =
                            ((((long long)(z2 * 64 + (t >> 5)) * 16 + z1) * 8
                              + (d >> 5) * 2 + ((t >> 4) & 1)) * 64
                             + ((d >> 3) & 3) * 16 + (t & 15)) * 8 + (d & 7);
                        ((ushort*)Cv)[idx] = (ushort)bfbits(val);
                    } else {
                        // vhimg[b][t>>5][h][d>>4][(t>>3)&3][d&15][t&7]
                        const int d = cn - 128;
                        const long long idx =
                            ((((long long)(z2 * 64 + (t >> 5)) * 16 + z1) * 8
                              + (d >> 4)) * 64
                             + ((t >> 3) & 3) * 16 + (d & 15)) * 8 + (t & 7);
                        ((ushort*)Cv2)[idx] = (ushort)bfbits(val);
                    }
                }
            }
        }
    }
}

// ---------------------------------------------------------------------------
// Fused f32 -> bf16 conversions (one launch). wkv_b converted AS-IS
// (h,256,512): rows 0-127/head = K-proj rows, 128-255 = V-proj rows —
// exactly the B matrix the merged K/V projection GEMM needs.
// ---------------------------------------------------------------------------
__global__ __launch_bounds__(256) void conv_all(
    const float* __restrict__ x, const float* __restrict__ wq,
    const float* __restrict__ wkva, const float* __restrict__ wo,
    const float* __restrict__ wkvb,
    ushort* __restrict__ x_bf, ushort* __restrict__ wq_bf,
    ushort* __restrict__ wkva_bf, ushort* __restrict__ wo_bf,
    ushort* __restrict__ wkvb_bf)
{
    const int bid = blockIdx.x;
    const int tid = threadIdx.x;
    if (bid < 8192) {                       // x: (4096,2048)
        const long long i = ((long long)bid * 256 + tid) * 4;
        float4 v = *(const float4*)&x[i];
        uint2 p; p.x = pack2bf(v.x, v.y); p.y = pack2bf(v.z, v.w);
        *(uint2*)&x_bf[i] = p;
    } else if (bid < 14336) {               // wq: (3072,2048)
        const long long i = ((long long)(bid - 8192) * 256 + tid) * 4;
        float4 v = *(const float4*)&wq[i];
        uint2 p; p.x = pack2bf(v.x, v.y); p.y = pack2bf(v.z, v.w);
        *(uint2*)&wq_bf[i] = p;
    } else if (bid < 15616) {               // wkva: (576,2048) pad to 640
        const int i = ((bid - 14336) * 256 + tid) * 4;
        const int r = i >> 11;
        uint2 p = make_uint2(0u, 0u);
        if (r < 576) {
            float4 v = *(const float4*)&wkva[i];
            p.x = pack2bf(v.x, v.y); p.y = pack2bf(v.z, v.w);
        }
        *(uint2*)&wkva_bf[i] = p;
    } else if (bid < 19712) {               // wo: (2048,2048)
        const long long i = ((long long)(bid - 15616) * 256 + tid) * 4;
        float4 v = *(const float4*)&wo[i];
        uint2 p; p.x = pack2bf(v.x, v.y); p.y = pack2bf(v.z, v.w);
        *(uint2*)&wo_bf[i] = p;
    } else {                                // wkv_b: (4096,512) linear
        const long long i = ((long long)(bid - 19712) * 256 + tid) * 4;
        float4 v = *(const float4*)&wkvb[i];
        uint2 p; p.x = pack2bf(v.x, v.y); p.y = pack2bf(v.z, v.w);
        *(uint2*)&wkvb_bf[i] = p;
    }
}

// ---------------------------------------------------------------------------
// kv post: bias add + rmsnorm(kv[:512]) -> kv_h bf16; rope(kv[512:576])
// written DIRECTLY in rimg fragment layout.
// ---------------------------------------------------------------------------
__global__ __launch_bounds__(64) void kv_post_kernel(
    const float* __restrict__ kv_raw, const float* __restrict__ bias,
    const float* __restrict__ w, const float* __restrict__ freqs,
    ushort* __restrict__ kv_h, uint* __restrict__ rimg)
{
    const int bs = blockIdx.x;
    const int lane = threadIdx.x;
    const float* src = kv_raw + (long long)bs * 640;
    ushort* dst = kv_h + (long long)bs * 576;

    const int c = 4 * lane;
    float4 v0 = *(const float4*)&src[c];
    float4 v1 = *(const float4*)&src[256 + c];
    float4 b0 = *(const float4*)&bias[c];
    float4 b1 = *(const float4*)&bias[256 + c];
    v0.x += b0.x; v0.y += b0.y; v0.z += b0.z; v0.w += b0.w;
    v1.x += b1.x; v1.y += b1.y; v1.z += b1.z; v1.w += b1.w;
    float ss = v0.x * v0.x + v0.y * v0.y + v0.z * v0.z + v0.w * v0.w +
               v1.x * v1.x + v1.y * v1.y + v1.z * v1.z + v1.w * v1.w;
#pragma unroll
    for (int o = 32; o; o >>= 1) ss += __shfl_xor(ss, o, 64);
    const float rs = rsqrtf(ss * (1.0f / 512.0f) + EPS_);

    float4 w0 = *(const float4*)&w[c];
    float4 w1 = *(const float4*)&w[256 + c];
    uint2 p0, p1;
    p0.x = pack2bf(v0.x * rs * w0.x, v0.y * rs * w0.y);
    p0.y = pack2bf(v0.z * rs * w0.z, v0.w * rs * w0.w);
    p1.x = pack2bf(v1.x * rs * w1.x, v1.y * rs * w1.y);
    p1.y = pack2bf(v1.z * rs * w1.z, v1.w * rs * w1.w);
    *(uint2*)&dst[c] = p0;
    *(uint2*)&dst[256 + c] = p1;

    if (lane < 32) {
        const int b = bs >> 11, s = bs & 2047;
        const int j = lane;
        const float f = freqs[s * 32 + j];
        float cs, sn;
        __sincosf(f, &sn, &cs);
        const float a  = src[512 + 2 * j]     + bias[512 + 2 * j];
        const float b2 = src[512 + 2 * j + 1] + bias[512 + 2 * j + 1];
        const uint p = pack2bf(a * cs - b2 * sn, a * sn + b2 * cs);
        const long long idx =
            (((long long)(b * 64 + (s >> 5)) * 4 + (j >> 4) * 2 + ((s >> 4) & 1)) * 64
             + ((j >> 2) & 3) * 16 + (s & 15)) * 4 + (j & 3);
        rimg[idx] = p;
    }
}

// ---------------------------------------------------------------------------
// MFMA flash attention v13 (unchanged): split-T + XCD-grouped.
// Grid (32 = h + 16b, 8 = pair, 2 = parity) = 512 blocks = 2/CU, uniform
// 34 tiles each; f32 partials + combine (constant-shift softmax).
// ---------------------------------------------------------------------------
__global__ __launch_bounds__(256, 2) void attn_kernel(
    const ushort* __restrict__ q192,  // (B,S,H,192), q*scale*log2e
    const uint4*  __restrict__ khimg, // (B,64,16,8,64) K_h frag chunks
    const uint4*  __restrict__ rimg,  // (B,64,4,64)   k_pe frag chunks
    const uint4*  __restrict__ vhimg, // (B,64,16,8,64) V_h^T frag chunks
    float* __restrict__ part_o,       // (512*2,128,128) f32 partial O
    float* __restrict__ part_l)       // (512*2,128)     f32 partial l
{
    __shared__ uint buf[2][20 * 256];   // 2 x 20 KB

    const int hb   = blockIdx.x;          // 0..31: h + 16*b (XCD = hb & 7)
    const int h    = hb & 15;
    const int b    = hb >> 4;
    const int p    = blockIdx.y;          // 0..7 (chunk pair)
    const int par  = blockIdx.z;          // tile parity
    const int tid  = threadIdx.x;
    const int wid  = tid >> 6;            // 0..3
    const int lane = tid & 63;
    const int m    = lane & 15;
    const int q4   = lane >> 4;
    const bool odd = q4 & 1;

    auto stage = [&](int bs, int it) {
        const long long tb = (long long)(b * 64 + it);
        const uint4* kb = khimg + ((tb * 16 + h) * 8) * 64;
        const uint4* rb = rimg  + (tb * 4) * 64;
        const uint4* vb = vhimg + ((tb * 16 + h) * 8) * 64;
        ushort* l = (ushort*)&buf[bs][0];
        gld_lds16((const ushort*)(kb + (wid    ) * 64 + lane), l + (wid     ) * 512);
        gld_lds16((const ushort*)(kb + (wid + 4) * 64 + lane), l + (wid +  4) * 512);
        gld_lds16((const ushort*)(rb + (wid    ) * 64 + lane), l + (wid +  8) * 512);
        gld_lds16((const ushort*)(vb + (wid    ) * 64 + lane), l + (wid + 12) * 512);
        gld_lds16((const ushort*)(vb + (wid + 4) * 64 + lane), l + (wid + 16) * 512);
    };

    int cur = 0;
    for (int pass = 0; pass < 2; ++pass) {
        const int chunk = pass ? p : (15 - p);
        const int row0a = chunk * 128 + wid * 16;
        const int row0b = row0a + 64;
        const int sRa   = row0a + m;
        const int sRb   = row0b + m;

        U4 qfa[6], qfb[6];
        {
            const uint4* qpa = (const uint4*)(q192 + ((long long)(b * S_ + sRa) * H_ + h) * 192);
            const uint4* qpb = (const uint4*)(q192 + ((long long)(b * S_ + sRb) * H_ + h) * 192);
#pragma unroll
            for (int f = 0; f < 6; ++f) { qfa[f].u = qpa[f * 4 + q4]; qfb[f].u = qpb[f * 4 + q4]; }
        }

        f32x4 oA[8], oB[8];
#pragma unroll
        for (int c = 0; c < 8; ++c) {
            oA[c] = (f32x4){0.f, 0.f, 0.f, 0.f};
            oB[c] = (f32x4){0.f, 0.f, 0.f, 0.f};
        }
        float lA = 0.0f, lB = 0.0f;

        auto softpack = [&](const f32x4 s0, const f32x4 s1, int t0v, int rw0,
                            float& lac) -> U4 {
            float p00, p01, p02, p03, p10, p11, p12, p13;
            if (t0v + 31 <= rw0) {            // fully unmasked tile
                p00 = exp2f(s0[0] - M0_); p01 = exp2f(s0[1] - M0_);
                p02 = exp2f(s0[2] - M0_); p03 = exp2f(s0[3] - M0_);
                p10 = exp2f(s1[0] - M0_); p11 = exp2f(s1[1] - M0_);
                p12 = exp2f(s1[2] - M0_); p13 = exp2f(s1[3] - M0_);
            } else {                          // diagonal tile
                const int sR = rw0 + m;
                const int tb0 = t0v + q4 * 4;
                const int tb1 = tb0 + 16;
                p00 = (tb0 + 0 <= sR) ? exp2f(s0[0] - M0_) : 0.0f;
                p01 = (tb0 + 1 <= sR) ? exp2f(s0[1] - M0_) : 0.0f;
                p02 = (tb0 + 2 <= sR) ? exp2f(s0[2] - M0_) : 0.0f;
                p03 = (tb0 + 3 <= sR) ? exp2f(s0[3] - M0_) : 0.0f;
                p10 = (tb1 + 0 <= sR) ? exp2f(s1[0] - M0_) : 0.0f;
                p11 = (tb1 + 1 <= sR) ? exp2f(s1[1] - M0_) : 0.0f;
                p12 = (tb1 + 2 <= sR) ? exp2f(s1[2] - M0_) : 0.0f;
                p13 = (tb1 + 3 <= sR) ? exp2f(s1[3] - M0_) : 0.0f;
            }
            lac += (p00 + p01) + (p02 + p03) + (p10 + p11) + (p12 + p13);
            uint X0 = cvtpk(p00, p01), X1 = cvtpk(p02, p03);
            uint Y0 = cvtpk(p10, p11), Y1 = cvtpk(p12, p13);
            asm("v_permlane32_swap_b32 %0, %1" : "+v"(X0), "+v"(Y0));
            asm("v_permlane32_swap_b32 %0, %1" : "+v"(X1), "+v"(Y1));
            uint u0 = odd ? X0 : Y0;
            uint u1 = odd ? X1 : Y1;
            uint w0 = (uint)__builtin_amdgcn_ds_swizzle((int)u0, 0x401F); // xor 16
            uint w1 = (uint)__builtin_amdgcn_ds_swizzle((int)u1, 0x401F);
            U4 bb;
            bb.u.x = odd ? w0 : X0;
            bb.u.y = odd ? w1 : X1;
            bb.u.z = odd ? Y0 : w0;
            bb.u.w = odd ? Y1 : w1;
            return bb;
        };

        const int nT2 = 2 * chunk + 2;        // parity-tiles in this pass
        __syncthreads();                 // all reads of prev pass's LDS done
        stage(cur, par);

        for (int v = 0; v < nT2; ++v) {
            const int it = 2 * v + par;
            const int t0 = it * 32;
            __syncthreads();             // drains vmcnt(0): buf[cur] staged
            if (v + 1 < nT2) stage(cur ^ 1, it + 2);   // overlap under compute
            __builtin_amdgcn_sched_barrier(0);

            const uint* bb0 = &buf[cur][0];
            const int abase = lane * 4;
            const bool liveB = (t0 <= row0b + 15);
            const bool liveA = (t0 <= row0a + 15);
            const bool twoA  = (t0 < row0a);
            const bool twoB  = (t0 < row0b);

            if (liveB) {
                f32x4 sA0 = (f32x4){0.f,0.f,0.f,0.f}, sA1 = (f32x4){0.f,0.f,0.f,0.f};
                f32x4 sB0 = (f32x4){0.f,0.f,0.f,0.f}, sB1 = (f32x4){0.f,0.f,0.f,0.f};

                if (twoA) {     // both substrips full: 4 MFMAs per read-pair
#pragma unroll
                    for (int f = 0; f < 6; ++f) {
                        const int ck = (f < 4) ? f * 2 : (f - 4) * 2 + 8;
                        U4 a0, a1;
                        a0.u = *(const uint4*)&bb0[ck * 256 + abase];
                        a1.u = *(const uint4*)&bb0[(ck + 1) * 256 + abase];
                        sA0 = __builtin_amdgcn_mfma_f32_16x16x32_bf16(a0.v, qfa[f].v, sA0, 0, 0, 0);
                        sB0 = __builtin_amdgcn_mfma_f32_16x16x32_bf16(a0.v, qfb[f].v, sB0, 0, 0, 0);
                        sA1 = __builtin_amdgcn_mfma_f32_16x16x32_bf16(a1.v, qfa[f].v, sA1, 0, 0, 0);
                        sB1 = __builtin_amdgcn_mfma_f32_16x16x32_bf16(a1.v, qfb[f].v, sB1, 0, 0, 0);
                    }
                } else {        // A diagonal/dead; B full or diagonal
#pragma unroll
                    for (int f = 0; f < 6; ++f) {
                        const int ck = (f < 4) ? f * 2 : (f - 4) * 2 + 8;
                        U4 a0;
                        a0.u = *(const uint4*)&bb0[ck * 256 + abase];
                        if (liveA)
                            sA0 = __builtin_amdgcn_mfma_f32_16x16x32_bf16(a0.v, qfa[f].v, sA0, 0, 0, 0);
                        sB0 = __builtin_amdgcn_mfma_f32_16x16x32_bf16(a0.v, qfb[f].v, sB0, 0, 0, 0);
                        if (twoB) {
                            U4 a1;
                            a1.u = *(const uint4*)&bb0[(ck + 1) * 256 + abase];
                            sB1 = __builtin_amdgcn_mfma_f32_16x16x32_bf16(a1.v, qfb[f].v, sB1, 0, 0, 0);
                        }
                    }
                }

                U4 bbB = softpack(sB0, sB1, t0, row0b, lB);
                if (liveA) {
                    U4 bbA = softpack(sA0, sA1, t0, row0a, lA);
#pragma unroll
                    for (int c = 0; c < 8; ++c) {
                        U4 av; av.u = *(const uint4*)&bb0[(12 + c) * 256 + abase];
                        oB[c] = __builtin_amdgcn_mfma_f32_16x16x32_bf16(av.v, bbB.v, oB[c], 0, 0, 0);
                        oA[c] = __builtin_amdgcn_mfma_f32_16x16x32_bf16(av.v, bbA.v, oA[c], 0, 0, 0);
                    }
                } else {
#pragma unroll
                    for (int c = 0; c < 8; ++c) {
                        U4 av; av.u = *(const uint4*)&bb0[(12 + c) * 256 + abase];
                        oB[c] = __builtin_amdgcn_mfma_f32_16x16x32_bf16(av.v, bbB.v, oB[c], 0, 0, 0);
                    }
                }
            }
            cur ^= 1;
        }

        // ---- epilogue: reduce l across q4 groups; store f32 partials
        lA += __shfl_xor(lA, 16, 64);
        lA += __shfl_xor(lA, 32, 64);
        lB += __shfl_xor(lB, 16, 64);
        lB += __shfl_xor(lB, 32, 64);

        const int cid  = (b * 16 + h) * 16 + chunk;
        const int slot = cid * 2 + par;
        float* po = part_o + (long long)slot * 16384;
        const int rA = wid * 16 + m;
        const int rB = rA + 64;
#pragma unroll
        for (int c = 0; c < 8; ++c) {
            *(f32x4*)&po[rA * 128 + c * 16 + q4 * 4] = oA[c];
            *(f32x4*)&po[rB * 128 + c * 16 + q4 * 4] = oB[c];
        }
        if (q4 == 0) {
            part_l[slot * 128 + rA] = lA;
            part_l[slot * 128 + rB] = lB;
        }
    }
}

// ---------------------------------------------------------------------------
// Combine the two parity partials: o = (o0+o1)/(l0+l1) -> o_h bf16.
// ---------------------------------------------------------------------------
__global__ __launch_bounds__(256) void combine_kernel(
    const float* __restrict__ part_o, const float* __restrict__ part_l,
    ushort* __restrict__ o_h)
{
    const int idx = blockIdx.x * 256 + threadIdx.x;    // 0..2,097,151
    const int d4  = (idx & 31) * 4;                    // 0..124
    const int r   = (idx >> 5) & 127;
    const int cid = idx >> 12;                         // 0..511
    const int chunk = cid & 15, h = (cid >> 4) & 15, b = cid >> 8;
    const long long s0 = (long long)(cid * 2) * 16384 + r * 128 + d4;
    float4 a = *(const float4*)&part_o[s0];
    float4 c = *(const float4*)&part_o[s0 + 16384];
    const float l = part_l[cid * 256 + r] + part_l[cid * 256 + 128 + r];
    const float inv = 1.0f / l;
    uint2 pk;
    pk.x = cvtpk((a.x + c.x) * inv, (a.y + c.y) * inv);
    pk.y = cvtpk((a.z + c.z) * inv, (a.w + c.w) * inv);
    const int s = chunk * 128 + r;
    *(uint2*)&o_h[(((long long)(b * S_ + s)) * H_ + h) * 128 + d4] = pk;
}

// ---------------------------------------------------------------------------
extern "C" void kernel_launch(void* const* d_in, const int* in_sizes, int n_in,
                              void* d_out, int out_size, void* d_ws, size_t ws_size,
                              hipStream_t stream)
{
    const float* x         = (const float*)d_in[0];
    const float* freqs     = (const float*)d_in[1];
    // d_in[2] = mask (unused: causal handled analytically)
    const float* wq_w      = (const float*)d_in[3];
    const float* wq_b      = (const float*)d_in[4];
    const float* wkv_a_w   = (const float*)d_in[5];
    const float* wkv_a_b   = (const float*)d_in[6];
    const float* kv_norm_w = (const float*)d_in[7];
    const float* wkv_b_w   = (const float*)d_in[8];
    const float* wo_w      = (const float*)d_in[9];
    const float* wo_b      = (const float*)d_in[10];
    float* out = (float*)d_out;

    // ---- workspace layout: persistent region + overlaid scratch
    char* w = (char*)d_ws;
    ushort* wo_bf   = (ushort*)w;  w += 8388608;    // (2048,2048) bf16
    uint4*  khimg   = (uint4*)w;   w += 16777216;   // (B,64,16,8,64)
    uint4*  vhimg   = (uint4*)w;   w += 16777216;   // (B,64,16,8,64)
    uint4*  rimg    = (uint4*)w;   w += 524288;     // (B,64,4,64)
    ushort* q192    = (ushort*)w;  w += 25165824;   // (4096,16,192) bf16
    ushort* o_h     = (ushort*)w;  w += 16777216;   // (4096,16,128) bf16
    char* SCR = w;                                  // scratch: ~68 MB
    // phase 1 (conv + GEMM1/2):
    ushort* x_bf    = (ushort*)(SCR);               // 16,777,216
    ushort* wq_bf   = (ushort*)(SCR + 16777216);    // 12,582,912
    ushort* wkva_bf = (ushort*)(SCR + 29360128);    //  2,621,440
    ushort* wkvb_bf = (ushort*)(SCR + 31981568);    //  4,194,304 (16,256,512), live thru step3
    float*  kv_raw  = (float*)(SCR + 36175872);     // 10,485,760 (dead after step2)
    // phase 2 overlay (x_bf dead after GEMM2):
    ushort* kv_h    = (ushort*)(SCR);               //  4,718,592 (over x_bf)
    // phase 3 overlays (attn partials; everything above dead by attn):
    float*  part_o  = (float*)(SCR);                // 67,108,864
    float*  part_l  = (float*)(SCR + 67108864);     //    524,288

    dim3 blk(256);

    // 0) all f32->bf16 conversions, one launch
    conv_all<<<dim3(21760), blk, 0, stream>>>(
        x, wq_w, wkv_a_w, wo_w, wkv_b_w,
        x_bf, wq_bf, wkva_bf, wo_bf, wkvb_bf);

    // 1) q192 = [x @ wq_w^T + wq_b, roped, *scale*log2e] bf16 (fused epilogue)
    mgemm<1><<<dim3(24, 32, 1), blk, 0, stream>>>(
        x_bf, 2048, 0LL, 0LL, wq_bf, 2048, 0LL, 0LL, wq_b, 1.0f,
        q192, 3072, 0LL, 0LL, 2048, 1, freqs, nullptr);

    // 2) kv_raw = x @ wkv_a_w^T (N=640 padded; bias folded into kv_post)
    mgemm<0><<<dim3(5, 32, 1), blk, 0, stream>>>(
        x_bf, 2048, 0LL, 0LL, wkva_bf, 2048, 0LL, 0LL, nullptr, 1.0f,
        kv_raw, 640, 0LL, 0LL, 2048, 1, nullptr, nullptr);

    // 3) bias + rmsnorm -> kv_h; rope -> rimg directly
    kv_post_kernel<<<dim3(4096), dim3(64), 0, stream>>>(
        kv_raw, wkv_a_b, kv_norm_w, freqs, kv_h, (uint*)rimg);

    // 4) MERGED per-head K/V projections (N=256: bx=0 -> khimg, bx=1 -> vhimg)
    //    B = wkv_b native (h,256,512); A = kv_h; 1024 blocks = 4/CU.
    mgemm<5><<<dim3(2, 16, 32), blk, 0, stream>>>(
        kv_h, 576, 0LL, (long long)S_ * 576,
        wkvb_bf, 512, 131072LL, 0LL, nullptr, 1.0f,
        khimg, 0, 0LL, 0LL, 512, 16, nullptr, vhimg);

    // 5) MFMA flash attention v13 (split-T, XCD-grouped) -> f32 partials
    attn_kernel<<<dim3(32, 8, 2), blk, 0, stream>>>(
        q192, khimg, rimg, vhimg, part_o, part_l);

    // 5b) combine parity partials -> o_h bf16
    combine_kernel<<<dim3(8192), blk, 0, stream>>>(part_o, part_l, o_h);

    // 6) out = o_h @ wo_w^T + wo_b
    mgemm<0><<<dim3(16, 32, 1), blk, 0, stream>>>(
        o_h, 2048, 0LL, 0LL, wo_bf, 2048, 0LL, 0LL, wo_b, 1.0f,
        out, 2048, 0LL, 0LL, 2048, 1, nullptr, nullptr);
}